// Round 5
// baseline (398.584 us; speedup 1.0000x reference)
//
#include <hip/hip_runtime.h>
#include <math.h>

// ---------------------------------------------------------------------------
// ConvexGenerator. Round 10: LDS-resident B panels for the grouped GEMMs.
// R9 post-mortem: direct-fp32 B staging REGRESSED logits (84us, FETCH 63->
// 173MB): 2x bytes, 16 scalar loads/lane/step, L2 panel thrash. Repack
// restored (it buys 2x compression + DMA-consumable layout). R9's profile
// shows the real disease: 30% HBM / 5.6% MFMA / 27% occ = per-step B latency.
// Fix: B panel (64 cols x 512 k bf16 = 64KB) loaded to LDS ONCE per block;
// M-tile 256 (8 waves, acc 32 VGPR/lane); K-loop touches global only for A
// (4 DMA/wave/step, depth-2, vmcnt(4)). B read from LDS every step, fetched
// once chip-wide. LDS = 2x32KB A-dbuf + 64KB panel = 128KB, 1 block/CU.
// logits: HID=1024 -> 2 sequential 512-k panel chunks, acc carried.
// synth: kci granularity 512 -> single panel per block (KE in {256,512}).
// Grids keep dense-dim-fast XCD spread (R7 lesson). mlp keeps R8 M64 core.
// Frag layouts (HW-verified): A[m=lane&15][k=(lane>>4)*8+j],
// B[k=(lane>>4)*8+j][n=lane&15], C/D col=lane&15 row=(lane>>4)*4+reg.
// ---------------------------------------------------------------------------

constexpr int B = 2048, LATENT = 128, C = 8, HID = 1024, D = 512, NMAX = 4096;

typedef __attribute__((ext_vector_type(8))) short bf16x8;
typedef __attribute__((ext_vector_type(4))) float f32x4;

#define GLD16(gsrc, ldst)                                                     \
    __builtin_amdgcn_global_load_lds(                                         \
        (const __attribute__((address_space(1))) unsigned int*)(gsrc),        \
        (__attribute__((address_space(3))) unsigned int*)(ldst), 16, 0, 0)

__device__ __forceinline__ int class_count(int c) {
    if (c < 6) return 1024 + 512 * c;
    return (c == 6) ? 3840 : 4096;
}

__device__ __forceinline__ float gelu_exact(float x) {
    return 0.5f * x * (1.0f + erff(x * 0.70710678118654752f));
}

__device__ __forceinline__ unsigned short f2bf(float f) {  // RNE
    unsigned int u = __float_as_uint(f);
    return (unsigned short)((u + 0x7fffu + ((u >> 16) & 1u)) >> 16);
}

__device__ __forceinline__ float waveMax(float v) {
    #pragma unroll
    for (int o = 32; o > 0; o >>= 1) v = fmaxf(v, __shfl_down(v, o));
    return v;
}
__device__ __forceinline__ float waveSum(float v) {
    #pragma unroll
    for (int o = 32; o > 0; o >>= 1) v += __shfl_down(v, o);
    return v;
}

// --- per-class gather lists (order-independent -> atomics replay-safe) ------
__global__ void k_gather(const int* __restrict__ cid, int* __restrict__ cnt,
                         int* __restrict__ idx) {
    int b = blockIdx.x * 256 + threadIdx.x;
    if (b < B) {
        int c = cid[b];
        int s = atomicAdd(&cnt[c], 1);
        idx[c * B + s] = b;
    }
}

// --- fp32 -> bf16 bulk convert (for z) --------------------------------------
__global__ void k_f2bf(const float* __restrict__ src,
                       unsigned short* __restrict__ dst, int n4) {
    int i = blockIdx.x * 256 + threadIdx.x;
    if (i < n4) {
        float4 v = *(const float4*)&src[(size_t)i * 4];
        ushort4 o = {f2bf(v.x), f2bf(v.y), f2bf(v.z), f2bf(v.w)};
        *(ushort4*)&dst[(size_t)i * 4] = o;
    }
}

// --- repack: src [R][Cc] fp32 -> bf16 MFMA B-frags --------------------------
// frag (ctile, rblk): lane=(q*16+n), elem j = src[rblk*32+q*8+j][ctile*16+n];
// frag index = (ctile*(R/32)+rblk)*512.
__global__ __launch_bounds__(256) void k_repack_frag(
    const float* __restrict__ src, unsigned short* __restrict__ dst,
    int R, int Cc, size_t srcStride, size_t dstStride, int limitMode) {
    const int cls = blockIdx.z;
    const int rb = blockIdx.x;
    const int c0 = blockIdx.y * 256;
    if (limitMode == 1 && c0 >= class_count(cls)) return;
    if (limitMode == 2 && rb * 32 >= class_count(cls)) return;
    src += (size_t)cls * srcStride;
    dst += (size_t)cls * dstStride;
    __shared__ float T[32][257];
    const int t = threadIdx.x;
    #pragma unroll
    for (int i = 0; i < 8; ++i) {
        int r = i * 4 + (t >> 6);
        int cc = (t & 63) * 4;
        float4 v = *(const float4*)&src[(size_t)(rb * 32 + r) * Cc + c0 + cc];
        T[r][cc] = v.x; T[r][cc + 1] = v.y; T[r][cc + 2] = v.z; T[r][cc + 3] = v.w;
    }
    __syncthreads();
    const int RB = R >> 5;
    #pragma unroll
    for (int i = 0; i < 4; ++i) {
        int ct = i * 4 + (t >> 6);
        int lane = t & 63;
        int n = lane & 15, q = lane >> 4;
        unsigned short tmp[8];
        #pragma unroll
        for (int j = 0; j < 8; ++j) tmp[j] = f2bf(T[q * 8 + j][ct * 16 + n]);
        *(uint4*)&dst[(((size_t)(c0 / 16 + ct)) * RB + rb) * 512 + lane * 8] =
            *(const uint4*)tmp;
    }
}

// ============== pipelined GEMM core, bf16-B-frag DMA (mlp, M64) =============
#define GEMM_PIPE_STAGE(bufsel, APSTEP, BPSTEP)                               \
    do {                                                                      \
        _Pragma("unroll") for (int i = 0; i < 2; ++i)                         \
            GLD16(ap[i] + (APSTEP), AsW + (bufsel) * 4096 + i * 512);         \
        _Pragma("unroll") for (int i = 0; i < 2; ++i)                         \
            GLD16(bp[i] + (BPSTEP), BsW + (bufsel) * 4096 + i * 512);         \
    } while (0)

#define GEMM_MFMA_PHASE(p_)                                                   \
    _Pragma("unroll") for (int kb = 0; kb < 2; ++kb) {                        \
        bf16x8 bfr[4];                                                        \
        _Pragma("unroll") for (int f = 0; f < 4; ++f)                         \
            bfr[f] = *(const bf16x8*)&Bs[(p_) * 4096 +                        \
                (kb * 4 + f) * 512 + lane * 8];                               \
        bf16x8 af = *(const bf16x8*)&As[(p_) * 4096 +                         \
            (wave * 16 + ln) * 64 +                                           \
            (((kb * 4 + lq) ^ (ln & 7)) * 8)];                                \
        _Pragma("unroll") for (int f = 0; f < 4; ++f)                         \
            acc[f] = __builtin_amdgcn_mfma_f32_16x16x32_bf16(                 \
                af, bfr[f], acc[f], 0, 0, 0);                                 \
    }

#define GEMM_PIPE_LOOP(KE, APSTEP, BPSTEP)                                    \
    {                                                                         \
        const int nk_ = (KE) >> 6;                                            \
        {                                                                     \
            const int k0 = 0;                                                 \
            (void)k0;                                                         \
            GEMM_PIPE_STAGE(0, APSTEP, BPSTEP);                               \
        }                                                                     \
        for (int ks_ = 0; ks_ < nk_; ++ks_) {                                 \
            const int p_ = ks_ & 1;                                           \
            if (ks_ + 1 < nk_) {                                              \
                const int k0 = (ks_ + 1) << 6;                                \
                GEMM_PIPE_STAGE(1 - p_, APSTEP, BPSTEP);                      \
                asm volatile("s_waitcnt vmcnt(4)" ::: "memory");              \
            } else {                                                          \
                asm volatile("s_waitcnt vmcnt(0)" ::: "memory");              \
            }                                                                 \
            asm volatile("s_barrier" ::: "memory");                           \
            __builtin_amdgcn_s_setprio(1);                                    \
            GEMM_MFMA_PHASE(p_)                                               \
            __builtin_amdgcn_s_setprio(0);                                    \
            asm volatile("s_barrier" ::: "memory");                           \
        }                                                                     \
    }

// ============== panel-resident GEMM core (logits/synth, M256) ===============
// 512 thr (8 waves), wave w owns rows w*32..w*32+31 (2 m-frags), N-tile 64.
// LDS: As dbuf 2 x [256][64] bf16 (chunk-swizzled rows) = 64KB + B panel
// 64 frag slots x 1KB = 64KB -> 128KB, 1 block/CU. Panel (<=64 frags = 4 f x
// <=16 kb) DMA'd once per 512-k chunk; K-loop stages ONLY A (4 GLD16/wave/
// step, depth-2, vmcnt(4)). B reads are LDS-only every step.
// Panel slot (f, kbl) at (f*16+kbl)*512; MFMA step ks reads slots ks*2+kb.
// Hazard ledger: A-buf p staged at step ks-1 top, drained by that step's
// vmcnt(4) + barrier; trailing barrier protects p from next overwrite; chunk
// boundary: trailing barrier = all waves done reading panel, vmcnt(0) after
// new panel+A0 issues covers both before first MFMA.
#define ASTAGE_PR(bufsel, koff)                                               \
    _Pragma("unroll") for (int i = 0; i < 4; ++i)                             \
        GLD16(ap[i] + (koff), AsW + (bufsel) * 16384 + i * 512);

#define PANEL_MFMA(p_, ks_)                                                   \
    _Pragma("unroll") for (int kb = 0; kb < 2; ++kb) {                        \
        bf16x8 bfr[4];                                                        \
        _Pragma("unroll") for (int f = 0; f < 4; ++f)                         \
            bfr[f] = *(const bf16x8*)&Bp[                                     \
                (f * 16 + (ks_) * 2 + kb) * 512 + lane * 8];                  \
        _Pragma("unroll") for (int mt = 0; mt < 2; ++mt) {                    \
            bf16x8 af = *(const bf16x8*)&As[(p_) * 16384 +                    \
                (wave * 32 + mt * 16 + ln) * 64 +                             \
                (((kb * 4 + lq) ^ (ln & 7)) * 8)];                            \
            _Pragma("unroll") for (int f = 0; f < 4; ++f)                     \
                acc[mt][f] = __builtin_amdgcn_mfma_f32_16x16x32_bf16(         \
                    af, bfr[f], acc[mt][f], 0, 0, 0);                         \
        }                                                                     \
    }

#define PANEL_KLOOP(NK, KBASE)                                                \
    {                                                                         \
        ASTAGE_PR(0, (KBASE));                                                \
        asm volatile("s_waitcnt vmcnt(0)" ::: "memory");                      \
        asm volatile("s_barrier" ::: "memory");                               \
        for (int ks = 0; ks < (NK); ++ks) {                                   \
            const int p_ = ks & 1;                                            \
            if (ks + 1 < (NK)) {                                              \
                ASTAGE_PR(1 - p_, (KBASE) + (ks + 1) * 64);                   \
                asm volatile("s_waitcnt vmcnt(4)" ::: "memory");              \
            } else {                                                          \
                asm volatile("s_waitcnt vmcnt(0)" ::: "memory");              \
            }                                                                 \
            asm volatile("s_barrier" ::: "memory");                           \
            __builtin_amdgcn_s_setprio(1);                                    \
            PANEL_MFMA(p_, ks)                                                \
            __builtin_amdgcn_s_setprio(0);                                    \
            asm volatile("s_barrier" ::: "memory");                           \
        }                                                                     \
    }

// --- MLP layer (dense rows): Out = gelu(A @ W + bias (+ onehot)) bf16 -------
__global__ __launch_bounds__(256, 8) void k_mlp_mfma(
    const unsigned short* __restrict__ A, const unsigned short* __restrict__ Bf,
    const float* __restrict__ bias, const float* __restrict__ Woh,
    const int* __restrict__ cid, unsigned short* __restrict__ Out, int K) {
    const int row0 = blockIdx.x * 64, col0 = blockIdx.y * 64;
    const int KBtot = K >> 5;
    const int t = threadIdx.x, wave = t >> 6, lane = t & 63;
    const int ln = lane & 15, lq = lane >> 4;
    __shared__ __align__(16) unsigned short As[2 * 64 * 64];
    __shared__ __align__(16) unsigned short Bs[2 * 8 * 512];
    const int arowl = lane >> 3;
    const int achk = (lane & 7) ^ arowl;
    const unsigned short* ap[2];
    #pragma unroll
    for (int i = 0; i < 2; ++i)
        ap[i] = A + (size_t)(row0 + wave * 16 + i * 8 + arowl) * K + achk * 8;
    const int kbw = wave >> 1;
    const unsigned short* bp[2];
    #pragma unroll
    for (int i = 0; i < 2; ++i) {
        int f = (wave * 2 + i) & 3;
        bp[i] = Bf + ((size_t)((col0 >> 4) + f) * KBtot + kbw) * 512 + lane * 8;
    }
    unsigned short* AsW = &As[wave * 1024];
    unsigned short* BsW = &Bs[(wave * 2) * 512];
    f32x4 acc[4] = {};
    GEMM_PIPE_LOOP(K, k0, (size_t)(k0 >> 5) * 512)
    #pragma unroll
    for (int reg = 0; reg < 4; ++reg) {
        int r = row0 + wave * 16 + lq * 4 + reg;
        const float* woh = Woh ? &Woh[(size_t)cid[r] * HID] : nullptr;
        #pragma unroll
        for (int f = 0; f < 4; ++f) {
            int col = col0 + f * 16 + ln;
            float v = acc[f][reg] + bias[col];
            if (woh) v += woh[col];
            Out[(size_t)r * HID + col] = f2bf(gelu_exact(v));
        }
    }
}

// --- grouped logits GEMM (panel-resident): L = t[g] @ Wa[c] + ba ------------
// Grid: (x = n-tile [dense -> XCD spread], y = class, z = 256-row slab).
__global__ __launch_bounds__(512, 1) void k_logits_mfma(
    const unsigned short* __restrict__ T, const unsigned short* __restrict__ Wf,
    const float* __restrict__ ba, const int* __restrict__ cnt,
    const int* __restrict__ idxs, float* __restrict__ L) {
    const int c = blockIdx.y;
    const int count = class_count(c);
    const int n0 = blockIdx.x * 64;
    if (n0 >= count) return;
    const int Mc = cnt[c];
    const int row0 = blockIdx.z * 256;
    if (row0 >= Mc) return;
    const int* idxc = idxs + c * B;
    const unsigned short* Wfc = Wf + (size_t)c * 4194304;
    const int t = threadIdx.x, wave = t >> 6, lane = t & 63;
    const int ln = lane & 15, lq = lane >> 4;
    __shared__ __align__(16) unsigned short As[2 * 256 * 64];  // 64 KB
    __shared__ __align__(16) unsigned short Bp[64 * 512];      // 64 KB panel
    const int arowl = lane >> 3;
    const int achk = (lane & 7) ^ arowl;
    const unsigned short* ap[4];
    #pragma unroll
    for (int i = 0; i < 4; ++i) {
        int g = idxc[min(row0 + wave * 32 + i * 8 + arowl, Mc - 1)];
        ap[i] = T + (size_t)g * HID + achk * 8;
    }
    unsigned short* AsW = &As[wave * 2048];
    f32x4 acc[2][4] = {};
    #pragma unroll
    for (int q = 0; q < 2; ++q) {
        // load 512-k panel chunk: 64 frags (4 f x 16 kb), 8 per wave
        #pragma unroll
        for (int j = 0; j < 8; ++j) {
            int fi = wave * 8 + j;                 // = f*16 + kbl
            GLD16(Wfc + ((size_t)((n0 >> 4) + (fi >> 4)) * 32 + q * 16 +
                         (fi & 15)) * 512 + lane * 8,
                  Bp + fi * 512);
        }
        PANEL_KLOOP(8, q * 512)
    }
    #pragma unroll
    for (int mt = 0; mt < 2; ++mt) {
        #pragma unroll
        for (int reg = 0; reg < 4; ++reg) {
            int r = row0 + wave * 32 + mt * 16 + lq * 4 + reg;
            if (r < Mc) {
                int g = idxc[r];
                #pragma unroll
                for (int f = 0; f < 4; ++f) {
                    int col = n0 + f * 16 + ln;
                    L[(size_t)g * NMAX + col] = acc[mt][f][reg] + ba[c * NMAX + col];
                }
            }
        }
    }
}

// --- softmax over first count cols; writes bf16 alpha -----------------------
__global__ __launch_bounds__(256) void k_softmax(const float* __restrict__ L,
                                                 unsigned short* __restrict__ Aout,
                                                 const int* __restrict__ cid) {
    const int b = blockIdx.x;
    const int n = class_count(cid[b]);
    const float* row = L + (size_t)b * NMAX;
    unsigned short* orow = Aout + (size_t)b * NMAX;
    const int t = threadIdx.x;
    float v[16];
    int nv = 0;
    float mx = -INFINITY;
    for (int i = t; i < n; i += 256) {
        float x = row[i];
        v[nv++] = x;
        mx = fmaxf(mx, x);
    }
    __shared__ float red[4], red2[4];
    float wm = waveMax(mx);
    int wid = t >> 6, lid = t & 63;
    if (lid == 0) red[wid] = wm;
    __syncthreads();
    float bmax = fmaxf(fmaxf(red[0], red[1]), fmaxf(red[2], red[3]));
    float s = 0.f;
    #pragma unroll
    for (int j = 0; j < 16; ++j)
        if (j < nv) { v[j] = expf(v[j] - bmax); s += v[j]; }
    float ws_ = waveSum(s);
    if (lid == 0) red2[wid] = ws_;
    __syncthreads();
    float inv = 1.0f / (red2[0] + red2[1] + red2[2] + red2[3]);
    int j = 0;
    for (int i = t; i < n; i += 256) orow[i] = f2bf(v[j++] * inv);
}

// --- grouped synth GEMM (panel-resident), split-K(512) + atomicAdd ----------
// Grid: (x = kci*8 + dtile [dtile low bits -> XCD spread], y = class,
//        z = 256-row slab). KE in {256, 512} -> one panel per block.
__global__ __launch_bounds__(512, 1) void k_synth_mfma(
    const unsigned short* __restrict__ Al, const unsigned short* __restrict__ Xf,
    const int* __restrict__ cnt, const int* __restrict__ idxs,
    float* __restrict__ Out) {
    const int c = blockIdx.y;
    const int count = class_count(c);
    const int dtile = blockIdx.x & 7, kci = blockIdx.x >> 3;
    const int kc0 = kci * 512;
    if (kc0 >= count) return;
    const int KE = min(kc0 + 512, count) - kc0;    // 256 or 512
    const int Mc = cnt[c];
    const int row0 = blockIdx.z * 256;
    if (row0 >= Mc) return;
    const int* idxc = idxs + c * B;
    const unsigned short* Xfc = Xf + (size_t)c * 2097152;
    const int d0 = dtile * 64;
    const int t = threadIdx.x, wave = t >> 6, lane = t & 63;
    const int ln = lane & 15, lq = lane >> 4;
    __shared__ __align__(16) unsigned short As[2 * 256 * 64];  // 64 KB
    __shared__ __align__(16) unsigned short Bp[64 * 512];      // 64 KB panel
    const int arowl = lane >> 3;
    const int achk = (lane & 7) ^ arowl;
    const unsigned short* ap[4];
    #pragma unroll
    for (int i = 0; i < 4; ++i) {
        int g = idxc[min(row0 + wave * 32 + i * 8 + arowl, Mc - 1)];
        ap[i] = Al + (size_t)g * NMAX + kc0 + achk * 8;
    }
    unsigned short* AsW = &As[wave * 2048];
    f32x4 acc[2][4] = {};
    const int nk = KE >> 6;                        // 4 or 8
    const int nkbl = KE >> 5;                      // 8 or 16
    const int kshift = (nkbl == 16) ? 4 : 3;
    const int pw = nkbl >> 1;                      // frags per wave (4 or 8)
    for (int j = 0; j < pw; ++j) {
        int fi = wave * pw + j;                    // f-major enumeration
        int f = fi >> kshift, kbl = fi & (nkbl - 1);
        GLD16(Xfc + ((size_t)((d0 >> 4) + f) * 128 + (kc0 >> 5) + kbl) * 512 +
                  lane * 8,
              Bp + (f * 16 + kbl) * 512);
    }
    PANEL_KLOOP(nk, 0)
    #pragma unroll
    for (int mt = 0; mt < 2; ++mt) {
        #pragma unroll
        for (int reg = 0; reg < 4; ++reg) {
            int r = row0 + wave * 32 + mt * 16 + lq * 4 + reg;
            if (r < Mc) {
                int g = idxc[r];
                #pragma unroll
                for (int f = 0; f < 4; ++f)
                    atomicAdd(&Out[(size_t)g * D + d0 + f * 16 + ln],
                              acc[mt][f][reg]);
            }
        }
    }
}

// ---------------------------------------------------------------------------
extern "C" void kernel_launch(void* const* d_in, const int* in_sizes, int n_in,
                              void* d_out, int out_size, void* d_ws,
                              size_t ws_size, hipStream_t stream) {
    const float* z    = (const float*)d_in[0];
    const int*   cid  = (const int*)d_in[1];
    const float* W1   = (const float*)d_in[2];
    const float* b1   = (const float*)d_in[3];
    const float* W2   = (const float*)d_in[4];
    const float* b2   = (const float*)d_in[5];
    const float* Wa   = (const float*)d_in[6];
    const float* ba   = (const float*)d_in[7];
    const float* Xbuf = (const float*)d_in[8];
    float* out = (float*)d_out;

    char* ws = (char*)d_ws;
    int*            cnt   = (int*)ws;                           // 256
    int*            idx   = (int*)(ws + 256);                   // 64 KB
    unsigned short* zbf   = (unsigned short*)(ws + 65792);      // 512 KB
    unsigned short* h     = (unsigned short*)(ws + 590080);     // 4 MB
    unsigned short* tbuf  = (unsigned short*)(ws + 4784384);    // 4 MB
    float*          L     = (float*)(ws + 8978688);             // 32 MB
    unsigned short* abuf  = (unsigned short*)(ws + 42533120);   // 16 MB
    unsigned short* Wf    = (unsigned short*)(ws + 59310336);   // 64 MB
    unsigned short* Xf    = (unsigned short*)(ws + 126419200);  // 32 MB
    unsigned short* W2f   = (unsigned short*)(ws + 159973632);  // 2 MB
    unsigned short* W1f   = (unsigned short*)(ws + 162070784);  // 256 KB

    hipMemsetAsync(cnt, 0, 256, stream);
    k_gather<<<dim3(B / 256), 256, 0, stream>>>(cid, cnt, idx);
    k_f2bf<<<dim3(256), 256, 0, stream>>>(z, zbf, B * LATENT / 4);
    k_repack_frag<<<dim3(4, 4, 1), 256, 0, stream>>>(W1, W1f, 128, HID, 0, 0, 0);
    k_repack_frag<<<dim3(32, 4, 1), 256, 0, stream>>>(W2, W2f, HID, HID, 0, 0, 0);
    k_repack_frag<<<dim3(32, 16, C), 256, 0, stream>>>(
        Wa, Wf, HID, NMAX, (size_t)HID * NMAX, 4194304, 1);
    k_repack_frag<<<dim3(128, 2, C), 256, 0, stream>>>(
        Xbuf, Xf, NMAX, D, (size_t)NMAX * D, 2097152, 2);
    k_mlp_mfma<<<dim3(B / 64, HID / 64), 256, 0, stream>>>(
        zbf, W1f, b1, W1 + (size_t)LATENT * HID, cid, h, LATENT);
    k_mlp_mfma<<<dim3(B / 64, HID / 64), 256, 0, stream>>>(
        h, W2f, b2, nullptr, cid, tbuf, HID);
    k_logits_mfma<<<dim3(NMAX / 64, C, B / 256), 512, 0, stream>>>(
        tbuf, Wf, ba, cnt, idx, L);
    k_softmax<<<dim3(B), 256, 0, stream>>>(L, abuf, cid);
    hipMemsetAsync(out, 0, (size_t)B * D * sizeof(float), stream);
    k_synth_mfma<<<dim3(64, C, B / 256), 512, 0, stream>>>(
        abuf, Xf, cnt, idx, out);
}

// Round 6
// 340.488 us; speedup vs baseline: 1.1706x; 1.1706x over previous
//
#include <hip/hip_runtime.h>
#include <math.h>

// ---------------------------------------------------------------------------
// ConvexGenerator. Round 11: R7 GEMM cores (best measured, 362us) + mega-
// fused preprocessing kernel.
// R10 post-mortem: panel-resident M256 (128KB LDS, 1 block/CU) regressed to
// 398us — block-level concurrency is the lifeblood of these latency-bound
// GEMMs (R6/R8/R10 all confirm). R7 config restored verbatim: M128 tile,
// 48KB LDS (3 blocks/CU), depth-2 counted-vmcnt pipeline, dense-dim-fast
// grids for XCD spread, repack path (R9 proved direct-fp32 B is worse).
// New: ALL pre-processing (gather via single-block shared-mem sort, z f2bf,
// W1/W2/Wa/Xbuf repacks, out-zero) fused into ONE flat-grid kernel k_prep;
// both hipMemsetAsync nodes eliminated. 13 stream nodes -> 6: saves launch
// gaps + tail-drains of 6 serialized pre-phase kernels, co-schedules the
// BW-bound repacks across the whole chip.
// Frag layouts (HW-verified): A[m=lane&15][k=(lane>>4)*8+j],
// B[k=(lane>>4)*8+j][n=lane&15], C/D col=lane&15 row=(lane>>4)*4+reg.
// ---------------------------------------------------------------------------

constexpr int B = 2048, LATENT = 128, C = 8, HID = 1024, D = 512, NMAX = 4096;

typedef __attribute__((ext_vector_type(8))) short bf16x8;
typedef __attribute__((ext_vector_type(4))) float f32x4;

#define GLD16(gsrc, ldst)                                                     \
    __builtin_amdgcn_global_load_lds(                                         \
        (const __attribute__((address_space(1))) unsigned int*)(gsrc),        \
        (__attribute__((address_space(3))) unsigned int*)(ldst), 16, 0, 0)

__device__ __forceinline__ int class_count(int c) {
    if (c < 6) return 1024 + 512 * c;
    return (c == 6) ? 3840 : 4096;
}

__device__ __forceinline__ float gelu_exact(float x) {
    return 0.5f * x * (1.0f + erff(x * 0.70710678118654752f));
}

__device__ __forceinline__ unsigned short f2bf(float f) {  // RNE
    unsigned int u = __float_as_uint(f);
    return (unsigned short)((u + 0x7fffu + ((u >> 16) & 1u)) >> 16);
}

__device__ __forceinline__ float waveMax(float v) {
    #pragma unroll
    for (int o = 32; o > 0; o >>= 1) v = fmaxf(v, __shfl_down(v, o));
    return v;
}
__device__ __forceinline__ float waveSum(float v) {
    #pragma unroll
    for (int o = 32; o > 0; o >>= 1) v += __shfl_down(v, o);
    return v;
}

// --- repack body: src [R][Cc] fp32 -> bf16 MFMA B-frags ---------------------
// frag (ctile, rblk): lane=(q*16+n), elem j = src[rblk*32+q*8+j][ctile*16+n];
// frag index = (ctile*(R/32)+rblk)*512.
__device__ void repack_body(const float* __restrict__ src,
                            unsigned short* __restrict__ dst,
                            int R, int Cc, int rb, int c0) {
    __shared__ float T[32][257];
    const int t = threadIdx.x;
    #pragma unroll
    for (int i = 0; i < 8; ++i) {
        int r = i * 4 + (t >> 6);
        int cc = (t & 63) * 4;
        float4 v = *(const float4*)&src[(size_t)(rb * 32 + r) * Cc + c0 + cc];
        T[r][cc] = v.x; T[r][cc + 1] = v.y; T[r][cc + 2] = v.z; T[r][cc + 3] = v.w;
    }
    __syncthreads();
    const int RB = R >> 5;
    #pragma unroll
    for (int i = 0; i < 4; ++i) {
        int ct = i * 4 + (t >> 6);
        int lane = t & 63;
        int n = lane & 15, q = lane >> 4;
        unsigned short tmp[8];
        #pragma unroll
        for (int j = 0; j < 8; ++j) tmp[j] = f2bf(T[q * 8 + j][ct * 16 + n]);
        *(uint4*)&dst[(((size_t)(c0 / 16 + ct)) * RB + rb) * 512 + lane * 8] =
            *(const uint4*)tmp;
    }
}

// --- fused preprocessing: one flat grid, range-dispatched -------------------
// [0,4096)      Wa repack   (rb 0..31, cb 0..15, cls 0..7), skip c0>=count
// [4096,6144)   Xbuf repack (rb 0..127, cb 0..1, cls 0..7), skip rb*32>=count
// [6144,6272)   W2 repack   (rb 0..31, cb 0..3)
// [6272,6288)   W1 repack   (rb 0..3,  cb 0..3)
// [6288,6544)   z fp32->bf16 (65536 float4s)
// [6544,6608)   out zero (4MB)
// [6608]        gather: single block, shared-mem per-class counting sort
__global__ __launch_bounds__(256) void k_prep(
    const float* __restrict__ z, const int* __restrict__ cid,
    const float* __restrict__ W1, const float* __restrict__ W2,
    const float* __restrict__ Wa, const float* __restrict__ Xbuf,
    unsigned short* __restrict__ zbf, unsigned short* __restrict__ W1f,
    unsigned short* __restrict__ W2f, unsigned short* __restrict__ Wf,
    unsigned short* __restrict__ Xf, int* __restrict__ cnt,
    int* __restrict__ idx, float* __restrict__ out) {
    const int bid = blockIdx.x;
    const int t = threadIdx.x;
    if (bid < 4096) {                              // Wa repack
        int cls = bid >> 9, rb = bid & 31, c0 = ((bid >> 5) & 15) * 256;
        if (c0 >= class_count(cls)) return;
        repack_body(Wa + (size_t)cls * HID * NMAX, Wf + (size_t)cls * 4194304,
                    HID, NMAX, rb, c0);
    } else if (bid < 6144) {                       // Xbuf repack
        int l = bid - 4096;
        int cls = l >> 8, rb = l & 127, c0 = ((l >> 7) & 1) * 256;
        if (rb * 32 >= class_count(cls)) return;
        repack_body(Xbuf + (size_t)cls * NMAX * D, Xf + (size_t)cls * 2097152,
                    NMAX, D, rb, c0);
    } else if (bid < 6272) {                       // W2 repack
        int l = bid - 6144;
        repack_body(W2, W2f, HID, HID, l & 31, (l >> 5) * 256);
    } else if (bid < 6288) {                       // W1 repack
        int l = bid - 6272;
        repack_body(W1, W1f, 128, HID, l & 3, (l >> 2) * 256);
    } else if (bid < 6544) {                       // z -> bf16
        int i = (bid - 6288) * 256 + t;            // < 65536 exactly
        float4 v = *(const float4*)&z[(size_t)i * 4];
        ushort4 o = {f2bf(v.x), f2bf(v.y), f2bf(v.z), f2bf(v.w)};
        *(ushort4*)&zbf[(size_t)i * 4] = o;
    } else if (bid < 6608) {                       // out zero
        int l = bid - 6544;
        float4 zero = {0.f, 0.f, 0.f, 0.f};
        #pragma unroll
        for (int i = 0; i < 16; ++i)
            *(float4*)&out[(size_t)l * 16384 + (size_t)(i * 256 + t) * 4] = zero;
    } else {                                       // gather (1 block)
        __shared__ int scnt[C];
        if (t < C) scnt[t] = 0;
        __syncthreads();
        for (int r = 0; r < B / 256; ++r) {
            int b = r * 256 + t;
            int c = cid[b];
            int s = atomicAdd(&scnt[c], 1);
            idx[c * B + s] = b;
        }
        __syncthreads();
        if (t < C) cnt[t] = scnt[t];
    }
}

// ================= pipelined global_load_lds GEMM core ======================
// 256 thr, 128-row M-tile (wave w rows w*32..w*32+31, 2 m-frags), 64-col
// N-tile (4 f-frags), BK=64 (2 kb). LDS double-buffered: As 2x128x64sh
// (row=128B, chunk-swizzled), Bs 2x8 frags x 1KB -> 48 KB (3 blocks/CU).
// Steady-state per step: issue next tile's 6 DMAs, s_waitcnt vmcnt(6)
// (current tile done, next tile's 6 stay in flight ACROSS the barrier),
// s_barrier, setprio(1), 16 MFMA/wave, setprio(0), s_barrier.
//
// Staging: lane l, issue i: tile row r=w*32+i*8+(l>>3), chunk (l&7)^(r&7)
// (r&7=(l>>3)&7), dst=As+buf*8192+w*2048+i*512 (+lane*16 by HW).
// Read: row r chunk c=kb*4+lq at position c^(r&7), r&7=ln&7.
// B: frag fi=w*2+i <-> (kb=fi>>2, f=fi&3); src kb-row = k0/32 + (w>>1).
// Hazard ledger: iter k computes buf[k&1]; its stage (buf[(k+1)&1]) is
// issued after iter k-1's trailing barrier (all waves done READING that
// buffer) and completes before iter k+1's leading barrier (own-wave
// vmcnt(6) + barrier covers cross-wave B frags). asm "memory" clobbers pin
// the DMA issues / ds_reads on the correct side of each wait/barrier.

#define GEMM_PIPE_STAGE(bufsel, APSTEP, BPSTEP)                               \
    do {                                                                      \
        _Pragma("unroll") for (int i = 0; i < 4; ++i)                         \
            GLD16(ap[i] + (APSTEP), AsW + (bufsel) * 8192 + i * 512);         \
        _Pragma("unroll") for (int i = 0; i < 2; ++i)                         \
            GLD16(bp[i] + (BPSTEP), BsW + (bufsel) * 4096 + i * 512);         \
    } while (0)

#define GEMM_PIPE_LOOP(KE, APSTEP, BPSTEP)                                    \
    {                                                                         \
        const int nk_ = (KE) >> 6;                                            \
        {                                                                     \
            const int k0 = 0;                                                 \
            (void)k0;                                                         \
            GEMM_PIPE_STAGE(0, APSTEP, BPSTEP);                               \
        }                                                                     \
        for (int ks_ = 0; ks_ < nk_; ++ks_) {                                 \
            const int p_ = ks_ & 1;                                           \
            if (ks_ + 1 < nk_) {                                              \
                const int k0 = (ks_ + 1) << 6;                                \
                GEMM_PIPE_STAGE(1 - p_, APSTEP, BPSTEP);                      \
                asm volatile("s_waitcnt vmcnt(6)" ::: "memory");              \
            } else {                                                          \
                asm volatile("s_waitcnt vmcnt(0)" ::: "memory");              \
            }                                                                 \
            asm volatile("s_barrier" ::: "memory");                           \
            __builtin_amdgcn_s_setprio(1);                                    \
            _Pragma("unroll") for (int kb = 0; kb < 2; ++kb) {                \
                bf16x8 bfr[4];                                                \
                _Pragma("unroll") for (int f = 0; f < 4; ++f)                 \
                    bfr[f] = *(const bf16x8*)&Bs[p_ * 4096 +                  \
                        (kb * 4 + f) * 512 + lane * 8];                       \
                _Pragma("unroll") for (int mt = 0; mt < 2; ++mt) {            \
                    bf16x8 af = *(const bf16x8*)&As[p_ * 8192 +               \
                        (wave * 32 + mt * 16 + ln) * 64 +                     \
                        (((kb * 4 + lq) ^ (ln & 7)) * 8)];                    \
                    _Pragma("unroll") for (int f = 0; f < 4; ++f)             \
                        acc[mt][f] = __builtin_amdgcn_mfma_f32_16x16x32_bf16( \
                            af, bfr[f], acc[mt][f], 0, 0, 0);                 \
                }                                                             \
            }                                                                 \
            __builtin_amdgcn_s_setprio(0);                                    \
            asm volatile("s_barrier" ::: "memory");                           \
        }                                                                     \
    }

// --- MLP layer (dense rows): Out = gelu(A @ W + bias (+ onehot)) bf16 -------
__global__ __launch_bounds__(256) void k_mlp_mfma(
    const unsigned short* __restrict__ A, const unsigned short* __restrict__ Bf,
    const float* __restrict__ bias, const float* __restrict__ Woh,
    const int* __restrict__ cid, unsigned short* __restrict__ Out, int K) {
    const int row0 = blockIdx.x * 128, col0 = blockIdx.y * 64;
    const int KBtot = K >> 5;
    const int t = threadIdx.x, wave = t >> 6, lane = t & 63;
    const int ln = lane & 15, lq = lane >> 4;
    __shared__ __align__(16) unsigned short As[2 * 128 * 64];
    __shared__ __align__(16) unsigned short Bs[2 * 8 * 512];
    const int arowl = lane >> 3;
    const int achk = (lane & 7) ^ arowl;
    const unsigned short* ap[4];
    #pragma unroll
    for (int i = 0; i < 4; ++i)
        ap[i] = A + (size_t)(row0 + wave * 32 + i * 8 + arowl) * K + achk * 8;
    const int kbw = wave >> 1;
    const unsigned short* bp[2];
    #pragma unroll
    for (int i = 0; i < 2; ++i) {
        int f = (wave * 2 + i) & 3;
        bp[i] = Bf + ((size_t)((col0 >> 4) + f) * KBtot + kbw) * 512 + lane * 8;
    }
    unsigned short* AsW = &As[wave * 2048];
    unsigned short* BsW = &Bs[(wave * 2) * 512];
    f32x4 acc[2][4] = {};
    GEMM_PIPE_LOOP(K, k0, (size_t)(k0 >> 5) * 512)
    #pragma unroll
    for (int mt = 0; mt < 2; ++mt) {
        #pragma unroll
        for (int reg = 0; reg < 4; ++reg) {
            int r = row0 + wave * 32 + mt * 16 + lq * 4 + reg;
            const float* woh = Woh ? &Woh[(size_t)cid[r] * HID] : nullptr;
            #pragma unroll
            for (int f = 0; f < 4; ++f) {
                int col = col0 + f * 16 + ln;
                float v = acc[mt][f][reg] + bias[col];
                if (woh) v += woh[col];
                Out[(size_t)r * HID + col] = f2bf(gelu_exact(v));
            }
        }
    }
}

// --- grouped logits GEMM: L[g, n0..n0+63] = t[g] @ Wa[c] + ba ---------------
// Grid: (x = n-tile [dense, spreads XCDs], y = class, z = row-block [sparse])
__global__ __launch_bounds__(256) void k_logits_mfma(
    const unsigned short* __restrict__ T, const unsigned short* __restrict__ Wf,
    const float* __restrict__ ba, const int* __restrict__ cnt,
    const int* __restrict__ idxs, float* __restrict__ L) {
    const int c = blockIdx.y;
    const int count = class_count(c);
    const int n0 = blockIdx.x * 64;
    if (n0 >= count) return;
    const int Mc = cnt[c];
    const int row0 = blockIdx.z * 128;
    if (row0 >= Mc) return;
    const int* idxc = idxs + c * B;
    const unsigned short* Wfc = Wf + (size_t)c * 4194304;
    const int t = threadIdx.x, wave = t >> 6, lane = t & 63;
    const int ln = lane & 15, lq = lane >> 4;
    __shared__ __align__(16) unsigned short As[2 * 128 * 64];
    __shared__ __align__(16) unsigned short Bs[2 * 8 * 512];
    const int arowl = lane >> 3;
    const int achk = (lane & 7) ^ arowl;
    const unsigned short* ap[4];
    #pragma unroll
    for (int i = 0; i < 4; ++i) {
        int g = idxc[min(row0 + wave * 32 + i * 8 + arowl, Mc - 1)];
        ap[i] = T + (size_t)g * HID + achk * 8;
    }
    const int kbw = wave >> 1;
    const unsigned short* bp[2];
    #pragma unroll
    for (int i = 0; i < 2; ++i) {
        int f = (wave * 2 + i) & 3;
        bp[i] = Wfc + ((size_t)((n0 >> 4) + f) * 32 + kbw) * 512 + lane * 8;
    }
    unsigned short* AsW = &As[wave * 2048];
    unsigned short* BsW = &Bs[(wave * 2) * 512];
    f32x4 acc[2][4] = {};
    GEMM_PIPE_LOOP(HID, k0, (size_t)(k0 >> 5) * 512)
    #pragma unroll
    for (int mt = 0; mt < 2; ++mt) {
        #pragma unroll
        for (int reg = 0; reg < 4; ++reg) {
            int r = row0 + wave * 32 + mt * 16 + lq * 4 + reg;
            if (r < Mc) {
                int g = idxc[r];
                #pragma unroll
                for (int f = 0; f < 4; ++f) {
                    int col = n0 + f * 16 + ln;
                    L[(size_t)g * NMAX + col] = acc[mt][f][reg] + ba[c * NMAX + col];
                }
            }
        }
    }
}

// --- softmax over first count cols; writes bf16 alpha -----------------------
__global__ __launch_bounds__(256) void k_softmax(const float* __restrict__ L,
                                                 unsigned short* __restrict__ Aout,
                                                 const int* __restrict__ cid) {
    const int b = blockIdx.x;
    const int n = class_count(cid[b]);
    const float* row = L + (size_t)b * NMAX;
    unsigned short* orow = Aout + (size_t)b * NMAX;
    const int t = threadIdx.x;
    float v[16];
    int nv = 0;
    float mx = -INFINITY;
    for (int i = t; i < n; i += 256) {
        float x = row[i];
        v[nv++] = x;
        mx = fmaxf(mx, x);
    }
    __shared__ float red[4], red2[4];
    float wm = waveMax(mx);
    int wid = t >> 6, lid = t & 63;
    if (lid == 0) red[wid] = wm;
    __syncthreads();
    float bmax = fmaxf(fmaxf(red[0], red[1]), fmaxf(red[2], red[3]));
    float s = 0.f;
    #pragma unroll
    for (int j = 0; j < 16; ++j)
        if (j < nv) { v[j] = expf(v[j] - bmax); s += v[j]; }
    float ws_ = waveSum(s);
    if (lid == 0) red2[wid] = ws_;
    __syncthreads();
    float inv = 1.0f / (red2[0] + red2[1] + red2[2] + red2[3]);
    int j = 0;
    for (int i = t; i < n; i += 256) orow[i] = f2bf(v[j++] * inv);
}

// --- grouped synth GEMM, split-K(1024) + atomicAdd --------------------------
// Grid: (x = kci*8 + dtile [dtile in low 3 bits -> spreads XCDs], y = class,
//        z = row-block [sparse]).
__global__ __launch_bounds__(256) void k_synth_mfma(
    const unsigned short* __restrict__ Al, const unsigned short* __restrict__ Xf,
    const int* __restrict__ cnt, const int* __restrict__ idxs,
    float* __restrict__ Out) {
    const int c = blockIdx.y;
    const int count = class_count(c);
    const int dtile = blockIdx.x & 7, kci = blockIdx.x >> 3;
    const int kc0 = kci * 1024;
    if (kc0 >= count) return;
    const int KE = min(kc0 + 1024, count) - kc0;   // multiple of 64
    const int Mc = cnt[c];
    const int row0 = blockIdx.z * 128;
    if (row0 >= Mc) return;
    const int* idxc = idxs + c * B;
    const unsigned short* Xfc = Xf + (size_t)c * 2097152;
    const int d0 = dtile * 64;
    const int t = threadIdx.x, wave = t >> 6, lane = t & 63;
    const int ln = lane & 15, lq = lane >> 4;
    __shared__ __align__(16) unsigned short As[2 * 128 * 64];
    __shared__ __align__(16) unsigned short Bs[2 * 8 * 512];
    const int arowl = lane >> 3;
    const int achk = (lane & 7) ^ arowl;
    const unsigned short* ap[4];
    #pragma unroll
    for (int i = 0; i < 4; ++i) {
        int g = idxc[min(row0 + wave * 32 + i * 8 + arowl, Mc - 1)];
        ap[i] = Al + (size_t)g * NMAX + kc0 + achk * 8;
    }
    const int kbw = wave >> 1;
    const unsigned short* bp[2];
    #pragma unroll
    for (int i = 0; i < 2; ++i) {
        int f = (wave * 2 + i) & 3;
        bp[i] = Xfc + ((size_t)((d0 >> 4) + f) * 128 + (kc0 >> 5) + kbw) * 512 + lane * 8;
    }
    unsigned short* AsW = &As[wave * 2048];
    unsigned short* BsW = &Bs[(wave * 2) * 512];
    f32x4 acc[2][4] = {};
    GEMM_PIPE_LOOP(KE, k0, (size_t)(k0 >> 5) * 512)
    #pragma unroll
    for (int mt = 0; mt < 2; ++mt) {
        #pragma unroll
        for (int reg = 0; reg < 4; ++reg) {
            int r = row0 + wave * 32 + mt * 16 + lq * 4 + reg;
            if (r < Mc) {
                int g = idxc[r];
                #pragma unroll
                for (int f = 0; f < 4; ++f)
                    atomicAdd(&Out[(size_t)g * D + d0 + f * 16 + ln], acc[mt][f][reg]);
            }
        }
    }
}

// ---------------------------------------------------------------------------
extern "C" void kernel_launch(void* const* d_in, const int* in_sizes, int n_in,
                              void* d_out, int out_size, void* d_ws,
                              size_t ws_size, hipStream_t stream) {
    const float* z    = (const float*)d_in[0];
    const int*   cid  = (const int*)d_in[1];
    const float* W1   = (const float*)d_in[2];
    const float* b1   = (const float*)d_in[3];
    const float* W2   = (const float*)d_in[4];
    const float* b2   = (const float*)d_in[5];
    const float* Wa   = (const float*)d_in[6];
    const float* ba   = (const float*)d_in[7];
    const float* Xbuf = (const float*)d_in[8];
    float* out = (float*)d_out;

    char* ws = (char*)d_ws;
    int*            cnt   = (int*)ws;                           // 256
    int*            idx   = (int*)(ws + 256);                   // 64 KB
    unsigned short* zbf   = (unsigned short*)(ws + 65792);      // 512 KB
    unsigned short* h     = (unsigned short*)(ws + 590080);     // 4 MB
    unsigned short* tbuf  = (unsigned short*)(ws + 4784384);    // 4 MB
    float*          L     = (float*)(ws + 8978688);             // 32 MB
    unsigned short* abuf  = (unsigned short*)(ws + 42533120);   // 16 MB
    unsigned short* Wf    = (unsigned short*)(ws + 59310336);   // 64 MB
    unsigned short* Xf    = (unsigned short*)(ws + 126419200);  // 32 MB
    unsigned short* W2f   = (unsigned short*)(ws + 159973632);  // 2 MB
    unsigned short* W1f   = (unsigned short*)(ws + 162070784);  // 256 KB

    k_prep<<<dim3(6609), 256, 0, stream>>>(
        z, cid, W1, W2, Wa, Xbuf, zbf, W1f, W2f, Wf, Xf, cnt, idx, out);
    k_mlp_mfma<<<dim3(B / 128, HID / 64), 256, 0, stream>>>(
        zbf, W1f, b1, W1 + (size_t)LATENT * HID, cid, h, LATENT);
    k_mlp_mfma<<<dim3(B / 128, HID / 64), 256, 0, stream>>>(
        h, W2f, b2, nullptr, cid, tbuf, HID);
    k_logits_mfma<<<dim3(NMAX / 64, C, B / 128), 256, 0, stream>>>(
        tbuf, Wf, ba, cnt, idx, L);
    k_softmax<<<dim3(B), 256, 0, stream>>>(L, abuf, cid);
    k_synth_mfma<<<dim3(32, C, B / 128), 256, 0, stream>>>(
        abuf, Xf, cnt, idx, out);
}

// Round 7
// 326.818 us; speedup vs baseline: 1.2196x; 1.0418x over previous
//
#include <hip/hip_runtime.h>
#include <math.h>

// ---------------------------------------------------------------------------
// ConvexGenerator. Round 12: overlap big repacks with MLP GEMMs via
// block-range fusion (single stream => separate launches are serial; fusion
// is the only overlap mechanism).
// R11 post-mortem: fused prep got 362->340; top-5 is only the harness 512MiB
// fill (87% HBM, untouchable). Remaining structure: prep's ~40us of BW-bound
// Wa/Xbuf repacks serialize BEFORE mlp1/mlp2, which then underfill the chip
// (256 blocks = 1/CU of 3 LDS slots). Fix: k_prep_small keeps only mlp1's
// deps (zbf, W1f, W2f, gather, out-zero ~4us); Wa-repack blocks ride the
// mlp1 launch (+4096 blocks), Xbuf-repack rides mlp2 (+2048). Repack LDS
// tile (33KB) is UNIONED onto the mlp As/Bs (one 48KB smem) so occupancy
// stays 3 blocks/CU: mlp takes 256 slots, repacks fill ~512 more and
// saturate HBM concurrently. Wf first used by logits (launch 4), Xf by
// synth (launch 6) — dependency-safe. GEMM cores unchanged (R7-best).
// Frag layouts (HW-verified): A[m=lane&15][k=(lane>>4)*8+j],
// B[k=(lane>>4)*8+j][n=lane&15], C/D col=lane&15 row=(lane>>4)*4+reg.
// ---------------------------------------------------------------------------

constexpr int B = 2048, LATENT = 128, C = 8, HID = 1024, D = 512, NMAX = 4096;

typedef __attribute__((ext_vector_type(8))) short bf16x8;
typedef __attribute__((ext_vector_type(4))) float f32x4;

#define GLD16(gsrc, ldst)                                                     \
    __builtin_amdgcn_global_load_lds(                                         \
        (const __attribute__((address_space(1))) unsigned int*)(gsrc),        \
        (__attribute__((address_space(3))) unsigned int*)(ldst), 16, 0, 0)

__device__ __forceinline__ int class_count(int c) {
    if (c < 6) return 1024 + 512 * c;
    return (c == 6) ? 3840 : 4096;
}

__device__ __forceinline__ float gelu_exact(float x) {
    return 0.5f * x * (1.0f + erff(x * 0.70710678118654752f));
}

__device__ __forceinline__ unsigned short f2bf(float f) {  // RNE
    unsigned int u = __float_as_uint(f);
    return (unsigned short)((u + 0x7fffu + ((u >> 16) & 1u)) >> 16);
}

__device__ __forceinline__ float waveMax(float v) {
    #pragma unroll
    for (int o = 32; o > 0; o >>= 1) v = fmaxf(v, __shfl_down(v, o));
    return v;
}
__device__ __forceinline__ float waveSum(float v) {
    #pragma unroll
    for (int o = 32; o > 0; o >>= 1) v += __shfl_down(v, o);
    return v;
}

// --- repack body: src [R][Cc] fp32 -> bf16 MFMA B-frags ---------------------
// frag (ctile, rblk): lane=(q*16+n), elem j = src[rblk*32+q*8+j][ctile*16+n];
// frag index = (ctile*(R/32)+rblk)*512. T is caller-provided LDS (33KB).
__device__ void repack_body(const float* __restrict__ src,
                            unsigned short* __restrict__ dst,
                            int R, int Cc, int rb, int c0, float (*T)[257]) {
    const int t = threadIdx.x;
    #pragma unroll
    for (int i = 0; i < 8; ++i) {
        int r = i * 4 + (t >> 6);
        int cc = (t & 63) * 4;
        float4 v = *(const float4*)&src[(size_t)(rb * 32 + r) * Cc + c0 + cc];
        T[r][cc] = v.x; T[r][cc + 1] = v.y; T[r][cc + 2] = v.z; T[r][cc + 3] = v.w;
    }
    __syncthreads();
    const int RB = R >> 5;
    #pragma unroll
    for (int i = 0; i < 4; ++i) {
        int ct = i * 4 + (t >> 6);
        int lane = t & 63;
        int n = lane & 15, q = lane >> 4;
        unsigned short tmp[8];
        #pragma unroll
        for (int j = 0; j < 8; ++j) tmp[j] = f2bf(T[q * 8 + j][ct * 16 + n]);
        *(uint4*)&dst[(((size_t)(c0 / 16 + ct)) * RB + rb) * 512 + lane * 8] =
            *(const uint4*)tmp;
    }
}

// --- small preprocessing: only what mlp1 needs + gather + out-zero ----------
// [0,256)    z fp32->bf16 (65536 float4s)
// [256,272)  W1 repack  (rb 0..3,  cb 0..3)
// [272,400)  W2 repack  (rb 0..31, cb 0..3)
// [400,464)  out zero (4MB)
// [464]      gather: single block, shared-mem per-class counting sort
__global__ __launch_bounds__(256) void k_prep_small(
    const float* __restrict__ z, const int* __restrict__ cid,
    const float* __restrict__ W1, const float* __restrict__ W2,
    unsigned short* __restrict__ zbf, unsigned short* __restrict__ W1f,
    unsigned short* __restrict__ W2f, int* __restrict__ cnt,
    int* __restrict__ idx, float* __restrict__ out) {
    __shared__ float T[32][257];
    const int bid = blockIdx.x;
    const int t = threadIdx.x;
    if (bid < 256) {                               // z -> bf16
        int i = bid * 256 + t;
        float4 v = *(const float4*)&z[(size_t)i * 4];
        ushort4 o = {f2bf(v.x), f2bf(v.y), f2bf(v.z), f2bf(v.w)};
        *(ushort4*)&zbf[(size_t)i * 4] = o;
    } else if (bid < 272) {                        // W1 repack
        int l = bid - 256;
        repack_body(W1, W1f, 128, HID, l & 3, (l >> 2) * 256, T);
    } else if (bid < 400) {                        // W2 repack
        int l = bid - 272;
        repack_body(W2, W2f, HID, HID, l & 31, (l >> 5) * 256, T);
    } else if (bid < 464) {                        // out zero
        int l = bid - 400;
        float4 zero = {0.f, 0.f, 0.f, 0.f};
        #pragma unroll
        for (int i = 0; i < 16; ++i)
            *(float4*)&out[(size_t)l * 16384 + (size_t)(i * 256 + t) * 4] = zero;
    } else {                                       // gather (1 block)
        __shared__ int scnt[C];
        if (t < C) scnt[t] = 0;
        __syncthreads();
        for (int r = 0; r < B / 256; ++r) {
            int b = r * 256 + t;
            int c = cid[b];
            int s = atomicAdd(&scnt[c], 1);
            idx[c * B + s] = b;
        }
        __syncthreads();
        if (t < C) cnt[t] = scnt[t];
    }
}

// ================= pipelined global_load_lds GEMM core ======================
// 256 thr, 128-row M-tile (wave w rows w*32..w*32+31, 2 m-frags), 64-col
// N-tile (4 f-frags), BK=64 (2 kb). LDS double-buffered: As 2x128x64sh
// (row=128B, chunk-swizzled), Bs 2x8 frags x 1KB -> 48 KB (3 blocks/CU).
// Steady-state per step: issue next tile's 6 DMAs, s_waitcnt vmcnt(6)
// (current tile done, next tile's 6 stay in flight ACROSS the barrier),
// s_barrier, setprio(1), 16 MFMA/wave, setprio(0), s_barrier.
// Hazard ledger: iter k computes buf[k&1]; its stage (buf[(k+1)&1]) is
// issued after iter k-1's trailing barrier and completes before iter k+1's
// leading barrier (own-wave vmcnt(6) + barrier covers cross-wave B frags).

#define GEMM_PIPE_STAGE(bufsel, APSTEP, BPSTEP)                               \
    do {                                                                      \
        _Pragma("unroll") for (int i = 0; i < 4; ++i)                         \
            GLD16(ap[i] + (APSTEP), AsW + (bufsel) * 8192 + i * 512);         \
        _Pragma("unroll") for (int i = 0; i < 2; ++i)                         \
            GLD16(bp[i] + (BPSTEP), BsW + (bufsel) * 4096 + i * 512);         \
    } while (0)

#define GEMM_PIPE_LOOP(KE, APSTEP, BPSTEP)                                    \
    {                                                                         \
        const int nk_ = (KE) >> 6;                                            \
        {                                                                     \
            const int k0 = 0;                                                 \
            (void)k0;                                                         \
            GEMM_PIPE_STAGE(0, APSTEP, BPSTEP);                               \
        }                                                                     \
        for (int ks_ = 0; ks_ < nk_; ++ks_) {                                 \
            const int p_ = ks_ & 1;                                           \
            if (ks_ + 1 < nk_) {                                              \
                const int k0 = (ks_ + 1) << 6;                                \
                GEMM_PIPE_STAGE(1 - p_, APSTEP, BPSTEP);                      \
                asm volatile("s_waitcnt vmcnt(6)" ::: "memory");              \
            } else {                                                          \
                asm volatile("s_waitcnt vmcnt(0)" ::: "memory");              \
            }                                                                 \
            asm volatile("s_barrier" ::: "memory");                           \
            __builtin_amdgcn_s_setprio(1);                                    \
            _Pragma("unroll") for (int kb = 0; kb < 2; ++kb) {                \
                bf16x8 bfr[4];                                                \
                _Pragma("unroll") for (int f = 0; f < 4; ++f)                 \
                    bfr[f] = *(const bf16x8*)&Bs[p_ * 4096 +                  \
                        (kb * 4 + f) * 512 + lane * 8];                       \
                _Pragma("unroll") for (int mt = 0; mt < 2; ++mt) {            \
                    bf16x8 af = *(const bf16x8*)&As[p_ * 8192 +               \
                        (wave * 32 + mt * 16 + ln) * 64 +                     \
                        (((kb * 4 + lq) ^ (ln & 7)) * 8)];                    \
                    _Pragma("unroll") for (int f = 0; f < 4; ++f)             \
                        acc[mt][f] = __builtin_amdgcn_mfma_f32_16x16x32_bf16( \
                            af, bfr[f], acc[mt][f], 0, 0, 0);                 \
                }                                                             \
            }                                                                 \
            __builtin_amdgcn_s_setprio(0);                                    \
            asm volatile("s_barrier" ::: "memory");                           \
        }                                                                     \
    }

// --- MLP layer + fused repack blocks ----------------------------------------
// bid<256: mlp (row0=(bid&15)*128, col0=(bid>>4)*64). bid>=256: repack.
// repMode 1: Wa (l=cls*512+cb*32+rb, skip c0>=count).
// repMode 2: Xbuf (l=cls*256+half*128+rb, skip rb*32>=count).
// LDS union: repack's 33KB T overlays the mlp's 48KB As/Bs; occupancy stays
// 3 blocks/CU so repack blocks co-run with the 256 mlp blocks (1/CU).
__global__ __launch_bounds__(256) void k_mlp_fused(
    const unsigned short* __restrict__ A, const unsigned short* __restrict__ Bf,
    const float* __restrict__ bias, const float* __restrict__ Woh,
    const int* __restrict__ cid, unsigned short* __restrict__ Out, int K,
    const float* __restrict__ repSrc, unsigned short* __restrict__ repDst,
    int repMode) {
    __shared__ __align__(16) char smem[49152];
    const int bid = blockIdx.x;
    if (bid >= 256) {
        float (*T)[257] = (float(*)[257])smem;
        int l = bid - 256;
        if (repMode == 1) {                        // Wa repack
            int cls = l >> 9, rb = l & 31, c0 = ((l >> 5) & 15) * 256;
            if (c0 >= class_count(cls)) return;
            repack_body(repSrc + (size_t)cls * HID * NMAX,
                        repDst + (size_t)cls * 4194304, HID, NMAX, rb, c0, T);
        } else {                                   // Xbuf repack
            int cls = l >> 8, rb = l & 127, c0 = ((l >> 7) & 1) * 256;
            if (rb * 32 >= class_count(cls)) return;
            repack_body(repSrc + (size_t)cls * NMAX * D,
                        repDst + (size_t)cls * 2097152, NMAX, D, rb, c0, T);
        }
        return;
    }
    unsigned short* As = (unsigned short*)smem;            // 32 KB
    unsigned short* Bs = (unsigned short*)(smem + 32768);  // 16 KB
    const int row0 = (bid & 15) * 128, col0 = (bid >> 4) * 64;
    const int KBtot = K >> 5;
    const int t = threadIdx.x, wave = t >> 6, lane = t & 63;
    const int ln = lane & 15, lq = lane >> 4;
    const int arowl = lane >> 3;
    const int achk = (lane & 7) ^ arowl;
    const unsigned short* ap[4];
    #pragma unroll
    for (int i = 0; i < 4; ++i)
        ap[i] = A + (size_t)(row0 + wave * 32 + i * 8 + arowl) * K + achk * 8;
    const int kbw = wave >> 1;
    const unsigned short* bp[2];
    #pragma unroll
    for (int i = 0; i < 2; ++i) {
        int f = (wave * 2 + i) & 3;
        bp[i] = Bf + ((size_t)((col0 >> 4) + f) * KBtot + kbw) * 512 + lane * 8;
    }
    unsigned short* AsW = &As[wave * 2048];
    unsigned short* BsW = &Bs[(wave * 2) * 512];
    f32x4 acc[2][4] = {};
    GEMM_PIPE_LOOP(K, k0, (size_t)(k0 >> 5) * 512)
    #pragma unroll
    for (int mt = 0; mt < 2; ++mt) {
        #pragma unroll
        for (int reg = 0; reg < 4; ++reg) {
            int r = row0 + wave * 32 + mt * 16 + lq * 4 + reg;
            const float* woh = Woh ? &Woh[(size_t)cid[r] * HID] : nullptr;
            #pragma unroll
            for (int f = 0; f < 4; ++f) {
                int col = col0 + f * 16 + ln;
                float v = acc[mt][f][reg] + bias[col];
                if (woh) v += woh[col];
                Out[(size_t)r * HID + col] = f2bf(gelu_exact(v));
            }
        }
    }
}

// --- grouped logits GEMM: L[g, n0..n0+63] = t[g] @ Wa[c] + ba ---------------
// Grid: (x = n-tile [dense, spreads XCDs], y = class, z = row-block [sparse])
__global__ __launch_bounds__(256) void k_logits_mfma(
    const unsigned short* __restrict__ T, const unsigned short* __restrict__ Wf,
    const float* __restrict__ ba, const int* __restrict__ cnt,
    const int* __restrict__ idxs, float* __restrict__ L) {
    const int c = blockIdx.y;
    const int count = class_count(c);
    const int n0 = blockIdx.x * 64;
    if (n0 >= count) return;
    const int Mc = cnt[c];
    const int row0 = blockIdx.z * 128;
    if (row0 >= Mc) return;
    const int* idxc = idxs + c * B;
    const unsigned short* Wfc = Wf + (size_t)c * 4194304;
    const int t = threadIdx.x, wave = t >> 6, lane = t & 63;
    const int ln = lane & 15, lq = lane >> 4;
    __shared__ __align__(16) unsigned short As[2 * 128 * 64];
    __shared__ __align__(16) unsigned short Bs[2 * 8 * 512];
    const int arowl = lane >> 3;
    const int achk = (lane & 7) ^ arowl;
    const unsigned short* ap[4];
    #pragma unroll
    for (int i = 0; i < 4; ++i) {
        int g = idxc[min(row0 + wave * 32 + i * 8 + arowl, Mc - 1)];
        ap[i] = T + (size_t)g * HID + achk * 8;
    }
    const int kbw = wave >> 1;
    const unsigned short* bp[2];
    #pragma unroll
    for (int i = 0; i < 2; ++i) {
        int f = (wave * 2 + i) & 3;
        bp[i] = Wfc + ((size_t)((n0 >> 4) + f) * 32 + kbw) * 512 + lane * 8;
    }
    unsigned short* AsW = &As[wave * 2048];
    unsigned short* BsW = &Bs[(wave * 2) * 512];
    f32x4 acc[2][4] = {};
    GEMM_PIPE_LOOP(HID, k0, (size_t)(k0 >> 5) * 512)
    #pragma unroll
    for (int mt = 0; mt < 2; ++mt) {
        #pragma unroll
        for (int reg = 0; reg < 4; ++reg) {
            int r = row0 + wave * 32 + mt * 16 + lq * 4 + reg;
            if (r < Mc) {
                int g = idxc[r];
                #pragma unroll
                for (int f = 0; f < 4; ++f) {
                    int col = n0 + f * 16 + ln;
                    L[(size_t)g * NMAX + col] = acc[mt][f][reg] + ba[c * NMAX + col];
                }
            }
        }
    }
}

// --- softmax over first count cols; writes bf16 alpha -----------------------
__global__ __launch_bounds__(256) void k_softmax(const float* __restrict__ L,
                                                 unsigned short* __restrict__ Aout,
                                                 const int* __restrict__ cid) {
    const int b = blockIdx.x;
    const int n = class_count(cid[b]);
    const float* row = L + (size_t)b * NMAX;
    unsigned short* orow = Aout + (size_t)b * NMAX;
    const int t = threadIdx.x;
    float v[16];
    int nv = 0;
    float mx = -INFINITY;
    for (int i = t; i < n; i += 256) {
        float x = row[i];
        v[nv++] = x;
        mx = fmaxf(mx, x);
    }
    __shared__ float red[4], red2[4];
    float wm = waveMax(mx);
    int wid = t >> 6, lid = t & 63;
    if (lid == 0) red[wid] = wm;
    __syncthreads();
    float bmax = fmaxf(fmaxf(red[0], red[1]), fmaxf(red[2], red[3]));
    float s = 0.f;
    #pragma unroll
    for (int j = 0; j < 16; ++j)
        if (j < nv) { v[j] = expf(v[j] - bmax); s += v[j]; }
    float ws_ = waveSum(s);
    if (lid == 0) red2[wid] = ws_;
    __syncthreads();
    float inv = 1.0f / (red2[0] + red2[1] + red2[2] + red2[3]);
    int j = 0;
    for (int i = t; i < n; i += 256) orow[i] = f2bf(v[j++] * inv);
}

// --- grouped synth GEMM, split-K(1024) + atomicAdd --------------------------
// Grid: (x = kci*8 + dtile [dtile in low 3 bits -> spreads XCDs], y = class,
//        z = row-block [sparse]).
__global__ __launch_bounds__(256) void k_synth_mfma(
    const unsigned short* __restrict__ Al, const unsigned short* __restrict__ Xf,
    const int* __restrict__ cnt, const int* __restrict__ idxs,
    float* __restrict__ Out) {
    const int c = blockIdx.y;
    const int count = class_count(c);
    const int dtile = blockIdx.x & 7, kci = blockIdx.x >> 3;
    const int kc0 = kci * 1024;
    if (kc0 >= count) return;
    const int KE = min(kc0 + 1024, count) - kc0;   // multiple of 64
    const int Mc = cnt[c];
    const int row0 = blockIdx.z * 128;
    if (row0 >= Mc) return;
    const int* idxc = idxs + c * B;
    const unsigned short* Xfc = Xf + (size_t)c * 2097152;
    const int d0 = dtile * 64;
    const int t = threadIdx.x, wave = t >> 6, lane = t & 63;
    const int ln = lane & 15, lq = lane >> 4;
    __shared__ __align__(16) unsigned short As[2 * 128 * 64];
    __shared__ __align__(16) unsigned short Bs[2 * 8 * 512];
    const int arowl = lane >> 3;
    const int achk = (lane & 7) ^ arowl;
    const unsigned short* ap[4];
    #pragma unroll
    for (int i = 0; i < 4; ++i) {
        int g = idxc[min(row0 + wave * 32 + i * 8 + arowl, Mc - 1)];
        ap[i] = Al + (size_t)g * NMAX + kc0 + achk * 8;
    }
    const int kbw = wave >> 1;
    const unsigned short* bp[2];
    #pragma unroll
    for (int i = 0; i < 2; ++i) {
        int f = (wave * 2 + i) & 3;
        bp[i] = Xfc + ((size_t)((d0 >> 4) + f) * 128 + (kc0 >> 5) + kbw) * 512 + lane * 8;
    }
    unsigned short* AsW = &As[wave * 2048];
    unsigned short* BsW = &Bs[(wave * 2) * 512];
    f32x4 acc[2][4] = {};
    GEMM_PIPE_LOOP(KE, k0, (size_t)(k0 >> 5) * 512)
    #pragma unroll
    for (int mt = 0; mt < 2; ++mt) {
        #pragma unroll
        for (int reg = 0; reg < 4; ++reg) {
            int r = row0 + wave * 32 + mt * 16 + lq * 4 + reg;
            if (r < Mc) {
                int g = idxc[r];
                #pragma unroll
                for (int f = 0; f < 4; ++f)
                    atomicAdd(&Out[(size_t)g * D + d0 + f * 16 + ln], acc[mt][f][reg]);
            }
        }
    }
}

// ---------------------------------------------------------------------------
extern "C" void kernel_launch(void* const* d_in, const int* in_sizes, int n_in,
                              void* d_out, int out_size, void* d_ws,
                              size_t ws_size, hipStream_t stream) {
    const float* z    = (const float*)d_in[0];
    const int*   cid  = (const int*)d_in[1];
    const float* W1   = (const float*)d_in[2];
    const float* b1   = (const float*)d_in[3];
    const float* W2   = (const float*)d_in[4];
    const float* b2   = (const float*)d_in[5];
    const float* Wa   = (const float*)d_in[6];
    const float* ba   = (const float*)d_in[7];
    const float* Xbuf = (const float*)d_in[8];
    float* out = (float*)d_out;

    char* ws = (char*)d_ws;
    int*            cnt   = (int*)ws;                           // 256
    int*            idx   = (int*)(ws + 256);                   // 64 KB
    unsigned short* zbf   = (unsigned short*)(ws + 65792);      // 512 KB
    unsigned short* h     = (unsigned short*)(ws + 590080);     // 4 MB
    unsigned short* tbuf  = (unsigned short*)(ws + 4784384);    // 4 MB
    float*          L     = (float*)(ws + 8978688);             // 32 MB
    unsigned short* abuf  = (unsigned short*)(ws + 42533120);   // 16 MB
    unsigned short* Wf    = (unsigned short*)(ws + 59310336);   // 64 MB
    unsigned short* Xf    = (unsigned short*)(ws + 126419200);  // 32 MB
    unsigned short* W2f   = (unsigned short*)(ws + 159973632);  // 2 MB
    unsigned short* W1f   = (unsigned short*)(ws + 162070784);  // 256 KB

    k_prep_small<<<dim3(465), 256, 0, stream>>>(
        z, cid, W1, W2, zbf, W1f, W2f, cnt, idx, out);
    k_mlp_fused<<<dim3(256 + 4096), 256, 0, stream>>>(
        zbf, W1f, b1, W1 + (size_t)LATENT * HID, cid, h, LATENT, Wa, Wf, 1);
    k_mlp_fused<<<dim3(256 + 2048), 256, 0, stream>>>(
        h, W2f, b2, nullptr, cid, tbuf, HID, Xbuf, Xf, 2);
    k_logits_mfma<<<dim3(NMAX / 64, C, B / 128), 256, 0, stream>>>(
        tbuf, Wf, ba, cnt, idx, L);
    k_softmax<<<dim3(B), 256, 0, stream>>>(L, abuf, cid);
    k_synth_mfma<<<dim3(32, C, B / 128), 256, 0, stream>>>(
        abuf, Xf, cnt, idx, out);
}